// Round 4
// baseline (9522.082 us; speedup 1.0000x reference)
//
#include <hip/hip_runtime.h>
#include <hip/hip_bf16.h>
#include <stdint.h>

// ---- problem constants ----
constexpr int LI   = 128;    // L_IN
constexpr int LO   = 64;     // L_OUT
constexpr int NB   = 32;     // batch
constexpr int HD   = 1024;   // H
constexpr int HHD  = 512;    // HH
constexpr int NLAY = 2;
constexpr int NV   = 32000;  // V_OUT
constexpr int SOST = 1;

// NOTE (round 4): all float tensors are FP32 (in_npz_mb=457.6 matches fp32
// sizes, not bf16). Compute uses bf16x3 split MFMA (~fp32 precision).

typedef __hip_bfloat16 bf16;
typedef __attribute__((ext_vector_type(8))) short bf16x8;
typedef __attribute__((ext_vector_type(4))) float f32x4;

__device__ __forceinline__ float b2f(bf16 x) { return __bfloat162float(x); }
__device__ __forceinline__ bf16  f2b(float x) { return __float2bfloat16(x); }
__device__ __forceinline__ float sigm(float x) { return 1.0f / (1.0f + expf(-x)); }

__device__ __forceinline__ f32x4 mfma(bf16x8 a, bf16x8 b, f32x4 c) {
    return __builtin_amdgcn_mfma_f32_16x16x32_bf16(a, b, c, 0, 0, 0);
}
// split product: (ah+al)*(bh+bl) ~= ah*bh + ah*bl + al*bh
__device__ __forceinline__ f32x4 mfma3(bf16x8 ah, bf16x8 al, bf16x8 bh, bf16x8 bl, f32x4 c) {
    c = mfma(ah, bh, c);
    c = mfma(ah, bl, c);
    c = mfma(al, bh, c);
    return c;
}
__device__ __forceinline__ bf16x8 ld8(const bf16* p) { return *(const bf16x8*)p; }

// split 8 consecutive fp32 into hi/lo bf16x8
__device__ __forceinline__ void split8(const float* p, bf16x8& h8, bf16x8& l8) {
    #pragma unroll
    for (int j = 0; j < 8; j++) {
        float v = p[j];
        bf16 h = f2b(v);
        bf16 l = f2b(v - b2f(h));
        ((bf16*)&h8)[j] = h;
        ((bf16*)&l8)[j] = l;
    }
}

// =====================================================================
// Split-precision MFMA GEMM: C[m,n] = sum_k A[m,k]*W[n,k] (+bias) (opt tanh)
// A,W,C fp32. 128-wide N tile, BM in {64,128}. 4 waves. z-batched.
// =====================================================================
template<int BM, bool BIAS, bool TANH>
__global__ __launch_bounds__(256) void gemm_k(
    const float* __restrict__ A, int64_t lda, int64_t sA,
    const float* __restrict__ W, int64_t ldw, int64_t sW,
    float* __restrict__ C, int64_t ldc, int64_t sC,
    const float* __restrict__ bias, int64_t sBias,
    int K)
{
    constexpr int FM = BM / 32;
    __shared__ __align__(16) bf16 Ahi[BM * 32], Alo[BM * 32];
    __shared__ __align__(16) bf16 Whi[128 * 32], Wlo[128 * 32];
    const int z    = blockIdx.z;
    const float* Ab = A + (int64_t)z * sA;
    const float* Wb = W + (int64_t)z * sW;
    const int n0   = blockIdx.x * 128;
    const int m0   = blockIdx.y * BM;
    const int tid  = threadIdx.x;
    const int lane = tid & 63, wid = tid >> 6;
    const int wm   = wid >> 1, wn = wid & 1;
    const int srow = lane >> 2;              // row within 16-row chunk
    const int skb  = (lane & 3) * 8;         // k offset (8 fp32)
    const int r16  = lane & 15;
    const int k8   = (lane >> 4) * 8;

    f32x4 acc[FM][4];
    #pragma unroll
    for (int i = 0; i < FM; i++)
        #pragma unroll
        for (int j = 0; j < 4; j++)
            acc[i][j] = f32x4{0.f, 0.f, 0.f, 0.f};

    for (int k0 = 0; k0 < K; k0 += 32) {
        for (int c = wid; c < BM / 16; c += 4) {
            bf16x8 h8, l8;
            split8(Ab + (int64_t)(m0 + c * 16 + srow) * lda + k0 + skb, h8, l8);
            *(bf16x8*)(Ahi + c * 512 + lane * 8) = h8;
            *(bf16x8*)(Alo + c * 512 + lane * 8) = l8;
        }
        for (int c = wid; c < 8; c += 4) {
            bf16x8 h8, l8;
            split8(Wb + (int64_t)(n0 + c * 16 + srow) * ldw + k0 + skb, h8, l8);
            *(bf16x8*)(Whi + c * 512 + lane * 8) = h8;
            *(bf16x8*)(Wlo + c * 512 + lane * 8) = l8;
        }
        __syncthreads();
        bf16x8 afh[FM], afl[FM], wfh[4], wfl[4];
        #pragma unroll
        for (int mt = 0; mt < FM; mt++) {
            const int off = (wm * (BM / 2) + mt * 16 + r16) * 32 + k8;
            afh[mt] = ld8(Ahi + off);
            afl[mt] = ld8(Alo + off);
        }
        #pragma unroll
        for (int nt = 0; nt < 4; nt++) {
            const int off = (wn * 64 + nt * 16 + r16) * 32 + k8;
            wfh[nt] = ld8(Whi + off);
            wfl[nt] = ld8(Wlo + off);
        }
        #pragma unroll
        for (int mt = 0; mt < FM; mt++)
            #pragma unroll
            for (int nt = 0; nt < 4; nt++)
                acc[mt][nt] = mfma3(afh[mt], afl[mt], wfh[nt], wfl[nt], acc[mt][nt]);
        __syncthreads();
    }
    #pragma unroll
    for (int nt = 0; nt < 4; nt++) {
        const int n = n0 + wn * 64 + nt * 16 + r16;
        float bv = 0.f;
        if constexpr (BIAS) bv = bias[(int64_t)z * sBias + n];
        #pragma unroll
        for (int mt = 0; mt < FM; mt++) {
            const int mb = m0 + wm * (BM / 2) + mt * 16 + (lane >> 4) * 4;
            #pragma unroll
            for (int r = 0; r < 4; r++) {
                float v = acc[mt][nt][r] + bv;
                if constexpr (TANH) v = tanhf(v);
                C[(int64_t)z * sC + (int64_t)(mb + r) * ldc + n] = v;
            }
        }
    }
}

// =====================================================================
// presplit: fp32 array -> hi/lo bf16 arrays
// =====================================================================
__global__ void presplit_k(const float* __restrict__ x, bf16* __restrict__ hi,
                           bf16* __restrict__ lo, int n)
{
    const int i = blockIdx.x * 256 + threadIdx.x;
    if (i < n) {
        float v = x[i];
        bf16 h = f2b(v);
        hi[i] = h;
        lo[i] = f2b(v - b2f(h));
    }
}

// =====================================================================
// Embedding gather (fp32 rows, 4KB each). shifted=1: teacher-forcing input.
// =====================================================================
__global__ void embed_k(const int* __restrict__ toks, const float* __restrict__ tab,
                        float* __restrict__ out, int shifted)
{
    const int row = blockIdx.x;
    int tok;
    if (shifted) {
        const int t = row / NB, b = row - t * NB;
        tok = (t == 0) ? SOST : toks[(t - 1) * NB + b];
    } else {
        tok = toks[row];
    }
    const uint4* s = (const uint4*)(tab + (int64_t)tok * HD);
    uint4* d = (uint4*)(out + (int64_t)row * HD);
    d[threadIdx.x] = s[threadIdx.x];   // 256 thr * 16B = 4096B = one fp32 row
}

// =====================================================================
// Encoder GRU step (one launch per s; blockIdx.y = direction). Split MFMA.
// =====================================================================
__global__ __launch_bounds__(64) void enc_step_k(
    const float* __restrict__ gi,     // [2][LI*NB][3*HHD] fp32 (+b_ih)
    const bf16* __restrict__ whhHi,   // [2][3*HHD][HHD] (this layer)
    const bf16* __restrict__ whhLo,
    const float* __restrict__ bhh,    // [2][3*HHD]
    float* __restrict__ h32,          // [2 par][2 dir][NB][HHD]
    bf16* __restrict__ hHi, bf16* __restrict__ hLo,
    float* __restrict__ Y,            // [LI][NB][HD] fp32
    float* __restrict__ dh32, bf16* __restrict__ dhHi, bf16* __restrict__ dhLo,
    int s)
{
    const int d = blockIdx.y;
    const int t = d ? (LI - 1 - s) : s;
    const int j0 = blockIdx.x * 16;
    const int lane = threadIdx.x;
    const int par = s & 1, npar = par ^ 1;
    const int r16 = lane & 15, k8 = (lane >> 4) * 8;
    const int64_t hbase = (int64_t)(par * 2 + d) * NB * HHD;
    const bf16* WdH = whhHi + (int64_t)d * 3 * HHD * HHD;
    const bf16* WdL = whhLo + (int64_t)d * 3 * HHD * HHD;

    f32x4 acc[2][3];
    #pragma unroll
    for (int i = 0; i < 2; i++)
        #pragma unroll
        for (int g = 0; g < 3; g++) acc[i][g] = f32x4{0.f, 0.f, 0.f, 0.f};

    for (int k0 = 0; k0 < HHD; k0 += 32) {
        bf16x8 a0h = ld8(hHi + hbase + r16 * HHD + k0 + k8);
        bf16x8 a0l = ld8(hLo + hbase + r16 * HHD + k0 + k8);
        bf16x8 a1h = ld8(hHi + hbase + (16 + r16) * HHD + k0 + k8);
        bf16x8 a1l = ld8(hLo + hbase + (16 + r16) * HHD + k0 + k8);
        #pragma unroll
        for (int g = 0; g < 3; g++) {
            const int64_t wo = (int64_t)(g * HHD + j0 + r16) * HHD + k0 + k8;
            bf16x8 wh = ld8(WdH + wo);
            bf16x8 wl = ld8(WdL + wo);
            acc[0][g] = mfma3(a0h, a0l, wh, wl, acc[0][g]);
            acc[1][g] = mfma3(a1h, a1l, wh, wl, acc[1][g]);
        }
    }
    const int j = j0 + r16;
    const float br = bhh[d * 3 * HHD + j];
    const float bz = bhh[d * 3 * HHD + HHD + j];
    const float bn = bhh[d * 3 * HHD + 2 * HHD + j];
    const float* gid = gi + ((int64_t)d * LI * NB + (int64_t)t * NB) * (3 * HHD);
    #pragma unroll
    for (int mt = 0; mt < 2; mt++)
        #pragma unroll
        for (int r = 0; r < 4; r++) {
            const int b = mt * 16 + (lane >> 4) * 4 + r;
            const float ir  = gid[b * 3 * HHD + j];
            const float iz  = gid[b * 3 * HHD + HHD + j];
            const float inn = gid[b * 3 * HHD + 2 * HHD + j];
            const float rg = sigm(ir + acc[mt][0][r] + br);
            const float zg = sigm(iz + acc[mt][1][r] + bz);
            const float ng = tanhf(inn + rg * (acc[mt][2][r] + bn));
            const float hold = h32[hbase + (int64_t)b * HHD + j];
            const float hnew = (1.f - zg) * ng + zg * hold;
            const int64_t no = (int64_t)(npar * 2 + d) * NB * HHD + (int64_t)b * HHD + j;
            bf16 hh = f2b(hnew);
            h32[no] = hnew;
            hHi[no] = hh;
            hLo[no] = f2b(hnew - b2f(hh));
            Y[((int64_t)t * NB + b) * HD + d * HHD + j] = hnew;
            if (s == LI - 1) {
                const int64_t dof = (int64_t)b * HD + d * HHD + j;
                dh32[dof] = hnew;
                dhHi[dof] = hh;
                dhLo[dof] = f2b(hnew - b2f(hh));
            }
        }
}

// =====================================================================
// Decoder step, layer0/layer1 pipelined across launches. Split MFMA.
// =====================================================================
__global__ __launch_bounds__(64) void dec_step_k(
    const float* __restrict__ gi0,    // [LO*NB][3*HD] fp32 (+b_ih0)
    const bf16* __restrict__ wih1Hi, const bf16* __restrict__ wih1Lo,
    const bf16* __restrict__ whh0Hi, const bf16* __restrict__ whh0Lo,
    const bf16* __restrict__ whh1Hi, const bf16* __restrict__ whh1Lo,
    const float* __restrict__ bih1,
    const float* __restrict__ bhh0,
    const float* __restrict__ bhh1,
    float* __restrict__ h32,          // [2 par][NLAY][NB][HD]
    bf16* __restrict__ hHi, bf16* __restrict__ hLo,
    float* __restrict__ rnn,          // [LO][NB][HD] fp32
    int s)
{
    const int lane = threadIdx.x;
    const int r16 = lane & 15, k8 = (lane >> 4) * 8;
    const int j0 = blockIdx.x * 16;
    const int j = j0 + r16;

    if (blockIdx.y == 0) {
        if (s >= LO) return;
        const int t = s, par = t & 1, npar = par ^ 1;
        const int64_t hb = (int64_t)(par * NLAY + 0) * NB * HD;
        f32x4 acc[2][3];
        #pragma unroll
        for (int i = 0; i < 2; i++)
            #pragma unroll
            for (int g = 0; g < 3; g++) acc[i][g] = f32x4{0.f, 0.f, 0.f, 0.f};
        for (int k0 = 0; k0 < HD; k0 += 32) {
            bf16x8 a0h = ld8(hHi + hb + r16 * HD + k0 + k8);
            bf16x8 a0l = ld8(hLo + hb + r16 * HD + k0 + k8);
            bf16x8 a1h = ld8(hHi + hb + (16 + r16) * HD + k0 + k8);
            bf16x8 a1l = ld8(hLo + hb + (16 + r16) * HD + k0 + k8);
            #pragma unroll
            for (int g = 0; g < 3; g++) {
                const int64_t wo = (int64_t)(g * HD + j0 + r16) * HD + k0 + k8;
                bf16x8 wh = ld8(whh0Hi + wo);
                bf16x8 wl = ld8(whh0Lo + wo);
                acc[0][g] = mfma3(a0h, a0l, wh, wl, acc[0][g]);
                acc[1][g] = mfma3(a1h, a1l, wh, wl, acc[1][g]);
            }
        }
        const float br = bhh0[j], bz = bhh0[HD + j], bn = bhh0[2 * HD + j];
        const float* gid = gi0 + (int64_t)t * NB * 3 * HD;
        #pragma unroll
        for (int mt = 0; mt < 2; mt++)
            #pragma unroll
            for (int r = 0; r < 4; r++) {
                const int b = mt * 16 + (lane >> 4) * 4 + r;
                const float ir  = gid[b * 3 * HD + j];
                const float iz  = gid[b * 3 * HD + HD + j];
                const float inn = gid[b * 3 * HD + 2 * HD + j];
                const float rg = sigm(ir + acc[mt][0][r] + br);
                const float zg = sigm(iz + acc[mt][1][r] + bz);
                const float ng = tanhf(inn + rg * (acc[mt][2][r] + bn));
                const float hold = h32[hb + (int64_t)b * HD + j];
                const float hnew = (1.f - zg) * ng + zg * hold;
                const int64_t no = (int64_t)(npar * NLAY + 0) * NB * HD + (int64_t)b * HD + j;
                bf16 hh = f2b(hnew);
                h32[no] = hnew;
                hHi[no] = hh;
                hLo[no] = f2b(hnew - b2f(hh));
            }
    } else {
        if (s < 1) return;
        const int t = s - 1;
        const int p0 = (t + 1) & 1;               // parity holding h0 AFTER step t
        const int p1 = t & 1, np1 = p1 ^ 1;
        const int64_t h0b = (int64_t)(p0 * NLAY + 0) * NB * HD;
        const int64_t h1b = (int64_t)(p1 * NLAY + 1) * NB * HD;
        f32x4 arz[2][2], ain[2], ahn[2];
        #pragma unroll
        for (int i = 0; i < 2; i++) {
            arz[i][0] = f32x4{0.f, 0.f, 0.f, 0.f};
            arz[i][1] = f32x4{0.f, 0.f, 0.f, 0.f};
            ain[i] = f32x4{0.f, 0.f, 0.f, 0.f};
            ahn[i] = f32x4{0.f, 0.f, 0.f, 0.f};
        }
        for (int k0 = 0; k0 < HD; k0 += 32) {
            bf16x8 x0h = ld8(hHi + h0b + r16 * HD + k0 + k8);
            bf16x8 x0l = ld8(hLo + h0b + r16 * HD + k0 + k8);
            bf16x8 x1h = ld8(hHi + h0b + (16 + r16) * HD + k0 + k8);
            bf16x8 x1l = ld8(hLo + h0b + (16 + r16) * HD + k0 + k8);
            bf16x8 y0h = ld8(hHi + h1b + r16 * HD + k0 + k8);
            bf16x8 y0l = ld8(hLo + h1b + r16 * HD + k0 + k8);
            bf16x8 y1h = ld8(hHi + h1b + (16 + r16) * HD + k0 + k8);
            bf16x8 y1l = ld8(hLo + h1b + (16 + r16) * HD + k0 + k8);
            const int64_t wr = (int64_t)(j0 + r16) * HD + k0 + k8;
            const int64_t wz = (int64_t)(HD + j0 + r16) * HD + k0 + k8;
            const int64_t wn = (int64_t)(2 * HD + j0 + r16) * HD + k0 + k8;
            bf16x8 wirh = ld8(wih1Hi + wr), wirl = ld8(wih1Lo + wr);
            bf16x8 whrh = ld8(whh1Hi + wr), whrl = ld8(whh1Lo + wr);
            bf16x8 wizh = ld8(wih1Hi + wz), wizl = ld8(wih1Lo + wz);
            bf16x8 whzh = ld8(whh1Hi + wz), whzl = ld8(whh1Lo + wz);
            bf16x8 winh = ld8(wih1Hi + wn), winl = ld8(wih1Lo + wn);
            bf16x8 whnh = ld8(whh1Hi + wn), whnl = ld8(whh1Lo + wn);
            arz[0][0] = mfma3(x0h, x0l, wirh, wirl, arz[0][0]);
            arz[0][0] = mfma3(y0h, y0l, whrh, whrl, arz[0][0]);
            arz[1][0] = mfma3(x1h, x1l, wirh, wirl, arz[1][0]);
            arz[1][0] = mfma3(y1h, y1l, whrh, whrl, arz[1][0]);
            arz[0][1] = mfma3(x0h, x0l, wizh, wizl, arz[0][1]);
            arz[0][1] = mfma3(y0h, y0l, whzh, whzl, arz[0][1]);
            arz[1][1] = mfma3(x1h, x1l, wizh, wizl, arz[1][1]);
            arz[1][1] = mfma3(y1h, y1l, whzh, whzl, arz[1][1]);
            ain[0] = mfma3(x0h, x0l, winh, winl, ain[0]);
            ain[1] = mfma3(x1h, x1l, winh, winl, ain[1]);
            ahn[0] = mfma3(y0h, y0l, whnh, whnl, ahn[0]);
            ahn[1] = mfma3(y1h, y1l, whnh, whnl, ahn[1]);
        }
        const float brr = bih1[j] + bhh1[j];
        const float bzz = bih1[HD + j] + bhh1[HD + j];
        const float bin = bih1[2 * HD + j];
        const float bhn = bhh1[2 * HD + j];
        #pragma unroll
        for (int mt = 0; mt < 2; mt++)
            #pragma unroll
            for (int r = 0; r < 4; r++) {
                const int b = mt * 16 + (lane >> 4) * 4 + r;
                const float rg = sigm(arz[mt][0][r] + brr);
                const float zg = sigm(arz[mt][1][r] + bzz);
                const float ng = tanhf(ain[mt][r] + bin + rg * (ahn[mt][r] + bhn));
                const float hold = h32[h1b + (int64_t)b * HD + j];
                const float hnew = (1.f - zg) * ng + zg * hold;
                const int64_t no = (int64_t)(np1 * NLAY + 1) * NB * HD + (int64_t)b * HD + j;
                bf16 hh = f2b(hnew);
                h32[no] = hnew;
                hHi[no] = hh;
                hLo[no] = f2b(hnew - b2f(hh));
                rnn[((int64_t)t * NB + b) * HD + j] = hnew;
            }
    }
}

// =====================================================================
// Softmax over ti (=128) per (to,b) row -> fp32 attn (also model output 1).
// =====================================================================
__global__ __launch_bounds__(64) void softmax_k(const float* __restrict__ sc,
                                                float* __restrict__ aout)
{
    const int row = blockIdx.x, l = threadIdx.x;
    float v0 = sc[row * LI + l], v1 = sc[row * LI + 64 + l];
    float m = fmaxf(v0, v1);
    #pragma unroll
    for (int o = 32; o > 0; o >>= 1) m = fmaxf(m, __shfl_xor(m, o));
    float e0 = expf(v0 - m), e1 = expf(v1 - m);
    float s = e0 + e1;
    #pragma unroll
    for (int o = 32; o > 0; o >>= 1) s += __shfl_xor(s, o);
    const float inv = 1.f / s;
    aout[row * LI + l] = e0 * inv;
    aout[row * LI + 64 + l] = e1 * inv;
}

// =====================================================================
// ctx[to,b,h] = sum_t attn[to,b,t]*enc[t,b,h] -> JIN[:, 0:HD]
// =====================================================================
__global__ __launch_bounds__(256) void ctx_k(const float* __restrict__ at,
                                             const float* __restrict__ enc,
                                             float* __restrict__ jin)
{
    const int b = blockIdx.y, h0 = blockIdx.x * 128;
    __shared__ __align__(16) float al[LO][LI];   // 32 KiB
    for (int i = threadIdx.x; i < LO * LI; i += 256) {
        const int to = i >> 7, ti = i & 127;
        al[to][ti] = at[(to * NB + b) * LI + ti];
    }
    __syncthreads();
    const int hc = h0 + (threadIdx.x & 127);
    const int rh = threadIdx.x >> 7;
    float acc[32];
    #pragma unroll
    for (int i = 0; i < 32; i++) acc[i] = 0.f;
    for (int t = 0; t < LI; t++) {
        const float ev = enc[((int64_t)t * NB + b) * HD + hc];
        #pragma unroll
        for (int i = 0; i < 32; i++) acc[i] += ev * al[rh * 32 + i][t];
    }
    #pragma unroll
    for (int i = 0; i < 32; i++)
        jin[((int64_t)(rh * 32 + i) * NB + b) * (2 * HD) + hc] = acc[i];
}

// copy rnn_out (fp32) into JIN[:, HD:2*HD]
__global__ void rnncopy_k(const float* __restrict__ rnn, float* __restrict__ jin)
{
    const int idx = blockIdx.x * 256 + threadIdx.x;  // uint4 = 4 fp32
    const int row = idx >> 8;                        // 256 uint4 per HD row
    const int c = idx & 255;
    ((uint4*)jin)[(int64_t)row * 512 + 256 + c] = ((const uint4*)rnn)[idx];
}

// =====================================================================
extern "C" void kernel_launch(void* const* d_in, const int* in_sizes, int n_in,
                              void* d_out, int out_size, void* d_ws, size_t ws_size,
                              hipStream_t stream)
{
    (void)in_sizes; (void)n_in; (void)out_size; (void)ws_size;
    const int*   in_tok   = (const int*)d_in[0];
    const int*   out_tok  = (const int*)d_in[2];
    const float* enc_emb  = (const float*)d_in[4];
    const float* enc_wih  = (const float*)d_in[5];
    const float* enc_whh  = (const float*)d_in[6];
    const float* enc_bih  = (const float*)d_in[7];
    const float* enc_bhh  = (const float*)d_in[8];
    const float* dec_emb  = (const float*)d_in[9];
    const float* dec_wih  = (const float*)d_in[10];
    const float* dec_whh  = (const float*)d_in[11];
    const float* dec_bih  = (const float*)d_in[12];
    const float* dec_bhh  = (const float*)d_in[13];
    const float* attn_W   = (const float*)d_in[14];
    const float* joiner_W = (const float*)d_in[15];
    const float* joiner_b = (const float*)d_in[16];
    const float* proj_W   = (const float*)d_in[17];
    const float* proj_b   = (const float*)d_in[18];
    float* logits   = (float*)d_out;
    float* attn_out = logits + (size_t)LO * NB * NV;

    // ---- scratch in d_out's logits region (250 MiB, fp32): 217 MiB used,
    // fully overwritten by the final logits GEMM; attn tail untouched until
    // softmax. Only VECS + h-state (10 MiB) in d_ws. All written-before-read.
    const size_t MB = 1ull << 20;
    char* o = (char*)d_out;
    float* XB0   = (float*)(o);              // 16 MiB enc embedded input
    float* XB1   = (float*)(o + 16 * MB);    // 16 MiB enc layer0 output
    float* EOUT  = (float*)(o + 32 * MB);    // 16 MiB enc_outputs
    float* PENC  = (float*)(o + 48 * MB);    // 16 MiB proj_enc
    float* GI    = (float*)(o + 64 * MB);    // 48 MiB enc gi (both dirs)
    float* DEMB  = (float*)(o + 112 * MB);   //  8 MiB dec embedded
    float* DGI0  = (float*)(o + 120 * MB);   // 24 MiB dec layer0 gi
    float* RNN   = (float*)(o + 144 * MB);   //  8 MiB rnn_out
    float* SC    = (float*)(o + 152 * MB);   //  1 MiB scores
    float* JIN   = (float*)(o + 153 * MB);   // 16 MiB cat(ctx, rnn)
    bf16* WencHi = (bf16*)(o + 169 * MB);    //  6 MiB enc_whh hi
    bf16* WencLo = (bf16*)(o + 175 * MB);    //  6 MiB enc_whh lo
    bf16* WdhHi  = (bf16*)(o + 181 * MB);    // 12 MiB dec_whh hi (both layers)
    bf16* WdhLo  = (bf16*)(o + 193 * MB);    // 12 MiB dec_whh lo
    bf16* Wih1Hi = (bf16*)(o + 205 * MB);    //  6 MiB dec_wih[1] hi
    bf16* Wih1Lo = (bf16*)(o + 211 * MB);    //  6 MiB dec_wih[1] lo

    char* w = (char*)d_ws;                   // 10 MiB total
    float* VECS = (float*)(w);                       // 8 MiB tanh(joiner)
    float* EH32 = (float*)(w + 8 * MB);              // 512 KiB
    bf16*  EHhi = (bf16*) (w + 8 * MB + 524288);     // 256 KiB
    bf16*  EHlo = (bf16*) (w + 8 * MB + 786432);     // 256 KiB
    float* DH32 = (float*)(w + 9 * MB);              // 512 KiB
    bf16*  DHhi = (bf16*) (w + 9 * MB + 524288);     // 256 KiB
    bf16*  DHlo = (bf16*) (w + 9 * MB + 786432);     // 256 KiB

    // ---- pre-split recurrent weights (fp32 -> bf16 hi/lo) ----
    const int nEnc = NLAY * 2 * 3 * HHD * HHD;   // 3,145,728
    const int nDhh = NLAY * 3 * HD * HD;         // 6,291,456
    const int nIh1 = 3 * HD * HD;                // 3,145,728
    presplit_k<<<dim3((nEnc + 255) / 256), dim3(256), 0, stream>>>(enc_whh, WencHi, WencLo, nEnc);
    presplit_k<<<dim3((nDhh + 255) / 256), dim3(256), 0, stream>>>(dec_whh, WdhHi, WdhLo, nDhh);
    presplit_k<<<dim3((nIh1 + 255) / 256), dim3(256), 0, stream>>>(dec_wih + (size_t)3 * HD * HD, Wih1Hi, Wih1Lo, nIh1);

    // ---- decoder prep ----
    embed_k<<<dim3(LO * NB), dim3(256), 0, stream>>>(out_tok, dec_emb, DEMB, 1);
    gemm_k<128, true, false><<<dim3(3 * HD / 128, LO * NB / 128, 1), 256, 0, stream>>>(
        DEMB, HD, 0, dec_wih, HD, 0, DGI0, 3 * HD, 0, dec_bih, 0, HD);

    // ---- encoder ----
    embed_k<<<dim3(LI * NB), dim3(256), 0, stream>>>(in_tok, enc_emb, XB0, 0);
    for (int l = 0; l < NLAY; l++) {
        const float* Xin = l ? XB1 : XB0;
        float* Yout = l ? EOUT : XB1;
        hipMemsetAsync(EH32, 0, (size_t)2 * 2 * NB * HHD * 4, stream);
        hipMemsetAsync(EHhi, 0, (size_t)2 * 2 * NB * HHD * 2, stream);
        hipMemsetAsync(EHlo, 0, (size_t)2 * 2 * NB * HHD * 2, stream);
        gemm_k<128, true, false><<<dim3(3 * HHD / 128, LI * NB / 128, 2), 256, 0, stream>>>(
            Xin, HD, 0,
            enc_wih + (size_t)l * 2 * 3 * HHD * HD, HD, (int64_t)3 * HHD * HD,
            GI, 3 * HHD, (int64_t)LI * NB * 3 * HHD,
            enc_bih + l * 2 * 3 * HHD, 3 * HHD, HD);
        for (int s = 0; s < LI; s++)
            enc_step_k<<<dim3(HHD / 16, 2), dim3(64), 0, stream>>>(
                GI,
                WencHi + (size_t)l * 2 * 3 * HHD * HHD,
                WencLo + (size_t)l * 2 * 3 * HHD * HHD,
                enc_bhh + l * 2 * 3 * HHD,
                EH32, EHhi, EHlo, Yout,
                DH32 + (size_t)l * NB * HD, DHhi + (size_t)l * NB * HD,
                DHlo + (size_t)l * NB * HD, s);
    }

    // proj_enc = enc_outputs @ attn_W^T
    gemm_k<128, false, false><<<dim3(HD / 128, LI * NB / 128, 1), 256, 0, stream>>>(
        EOUT, HD, 0, attn_W, HD, 0, PENC, HD, 0, nullptr, 0, HD);

    // ---- decoder recurrence ----
    for (int s = 0; s <= LO; s++)
        dec_step_k<<<dim3(HD / 16, 2), dim3(64), 0, stream>>>(
            DGI0,
            Wih1Hi, Wih1Lo,
            WdhHi, WdhLo,
            WdhHi + (size_t)3 * HD * HD, WdhLo + (size_t)3 * HD * HD,
            dec_bih + 3 * HD, dec_bhh, dec_bhh + 3 * HD,
            DH32, DHhi, DHlo, RNN, s);

    // ---- batched epilogue ----
    gemm_k<64, false, false><<<dim3(1, 1, NB), 256, 0, stream>>>(
        RNN, (int64_t)NB * HD, HD, PENC, (int64_t)NB * HD, HD,
        SC, (int64_t)NB * LI, LI, nullptr, 0, HD);
    softmax_k<<<dim3(LO * NB), dim3(64), 0, stream>>>(SC, attn_out);
    ctx_k<<<dim3(HD / 128, NB), dim3(256), 0, stream>>>(attn_out, EOUT, JIN);
    rnncopy_k<<<dim3(LO * NB * HD / 4 / 256), dim3(256), 0, stream>>>(RNN, JIN);
    gemm_k<128, true, true><<<dim3(HD / 128, LO * NB / 128, 1), 256, 0, stream>>>(
        JIN, 2 * HD, 0, joiner_W, 2 * HD, 0, VECS, HD, 0, joiner_b, 0, 2 * HD);
    gemm_k<128, true, false><<<dim3(NV / 128, LO * NB / 128, 1), 256, 0, stream>>>(
        VECS, HD, 0, proj_W, HD, 0, logits, NV, 0, proj_b, 0, HD);
}